// Round 4
// baseline (1556.087 us; speedup 1.0000x reference)
//
#include <hip/hip_runtime.h>

#define NB 64
#define NS 2048
#define ND 64
#define KSTEP 64
#define NIT (NS / KSTEP)  // 32

typedef __bf16 bf16x8 __attribute__((ext_vector_type(8)));
typedef float f32x4 __attribute__((ext_vector_type(4)));
typedef float f32x16 __attribute__((ext_vector_type(16)));
typedef unsigned int u32;
typedef u32 u32x4 __attribute__((ext_vector_type(4)));

__device__ __forceinline__ unsigned short f2bs(float x) {
  __bf16 h = (__bf16)x;
  return __builtin_bit_cast(unsigned short, h);
}

__device__ __forceinline__ bf16x8 cvt8(f32x4 a, f32x4 b) {
  bf16x8 r;
  r[0] = (__bf16)a[0]; r[1] = (__bf16)a[1]; r[2] = (__bf16)a[2]; r[3] = (__bf16)a[3];
  r[4] = (__bf16)b[0]; r[5] = (__bf16)b[1]; r[6] = (__bf16)b[2]; r[7] = (__bf16)b[3];
  return r;
}

// mask (int 0/1) -> additive bias (0 / -1e9), written to workspace once per launch
__global__ __launch_bounds__(256) void mask_to_bias_kernel(
    const int4* __restrict__ M4, float4* __restrict__ B4, int n4) {
  int i = blockIdx.x * 256 + threadIdx.x;
  if (i < n4) {
    int4 m = M4[i];
    float4 o;
    o.x = m.x ? 0.f : -1e9f;
    o.y = m.y ? 0.f : -1e9f;
    o.z = m.z ? 0.f : -1e9f;
    o.w = m.w ? 0.f : -1e9f;
    B4[i] = o;
  }
}

// mfma_f32_32x32x16_bf16 layout facts (HW-verified rounds 1-3):
//   A: lane holds A[row = l&31][k-slot]; B: B[k-slot][col = l&31] (mirrored)
//   D: col = l&31, row = (reg&3) + 8*(reg>>2) + 4*(l>>5)
// QK^T: A=K, B=Q -> lane owns W[q = l&31][k = 4h + (reg&3) + 8*(reg>>2)].
// PV:   A = V^T staged with kappa(k16) = 8*(k16>>2 &1) + 4*(k16>>3) + (k16&3)
//       column permutation so B = W comes straight from QK^T D registers.
// 8 waves: waves 0-3 handle k-half 0, waves 4-7 k-half 1, same 128 q-rows;
// rowsums and ctx partials pair-combined through LDS.
template <bool USEB>
__global__ __launch_bounds__(512, 6) void DotProductAttention_22436909154804_kernel(
    const float* __restrict__ Q, const float* __restrict__ K,
    const float* __restrict__ V, const int* __restrict__ M,
    const float* __restrict__ Bias, float* __restrict__ ctx,
    float* __restrict__ wts) {
  __shared__ __attribute__((aligned(16))) unsigned short Kt[2][64][68];  // [k][d]
  __shared__ __attribute__((aligned(16))) unsigned short Vt[2][64][68];  // [d][perm k]
  __shared__ float Rs[2][128];

  const int tid  = threadIdx.x;
  const int lane = tid & 63;
  const int w    = tid >> 6;   // 0..7
  const int wq   = w & 3;      // q-group
  const int kt   = w >> 2;     // k-half 0/1
  const int q    = lane & 31;
  const int h    = lane >> 5;

  // XCD-bijective swizzle: 1024 blocks, 8 XCDs -> same-batch blocks share an XCD
  const int bid = blockIdx.x;
  const int vb  = (bid & 7) * 128 + (bid >> 3);
  const int b   = vb >> 4;
  const int qt  = vb & 15;
  const int q0  = qt * 128 + wq * 32;
  const size_t bq = (size_t)b * NS;

  // Q B-frags: chunk c covers d = 16c + 8h + s
  const float* qp = Q + (bq + q0 + q) * ND + 8 * h;
  bf16x8 qf[4];
#pragma unroll
  for (int c = 0; c < 4; ++c)
    qf[c] = cvt8(*(const f32x4*)(qp + 16 * c), *(const f32x4*)(qp + 16 * c + 4));

  const float* Kb = K + bq * ND;
  const float* Vb = V + bq * ND;
  const int*   Mr = M + (size_t)(q0 + q) * NS + kt * 32;     // mask: batch-shared
  const float* Br = USEB ? (Bias + (size_t)(q0 + q) * NS + kt * 32) : nullptr;

  // staging maps (512 threads, 64x64 tiles)
  const int skr = tid >> 3;        // K row 0..63
  const int skd = (tid & 7) * 8;   // K d-chunk
  const int sva = tid >> 4;        // V k-pair 0..31
  const int svd = (tid & 15) * 4;  // V d base
  const int c16 = (2 * sva) & 15;
  const int vcol = 16 * ((2 * sva) >> 4) + 8 * ((c16 >> 2) & 1) + (c16 & 3) + 4 * ((c16 >> 3) & 1);

  f32x4 kst[2], vst[2];
  auto issueK = [&](int kb) {
    const float* p = Kb + (size_t)(kb + skr) * ND + skd;
    kst[0] = *(const f32x4*)p;
    kst[1] = *(const f32x4*)(p + 4);
  };
  auto writeK = [&](int buf) {
    *(bf16x8*)&Kt[buf][skr][skd] = cvt8(kst[0], kst[1]);
  };
  auto issueV = [&](int kb) {
    const float* p = Vb + (size_t)(kb + 2 * sva) * ND + svd;
    vst[0] = *(const f32x4*)p;
    vst[1] = *(const f32x4*)(p + ND);
  };
  auto writeV = [&](int buf) {
#pragma unroll
    for (int j = 0; j < 4; ++j)
      *(u32*)&Vt[buf][svd + j][vcol] = (u32)f2bs(vst[0][j]) | ((u32)f2bs(vst[1][j]) << 16);
  };

  // one 32x32 QK^T tile for this wave's k-half
  auto qk_tile = [&](int cur) -> f32x16 {
    f32x16 d = {};
#pragma unroll
    for (int c = 0; c < 4; ++c) {
      bf16x8 a = *(const bf16x8*)&Kt[cur][kt * 32 + q][16 * c + 8 * h];
      d = __builtin_amdgcn_mfma_f32_32x32x16_bf16(a, qf[c], d, 0, 0, 0);
    }
    return d;
  };

  // ---------------- Phase 1: row sums ----------------
  float rs = 0.f;
  issueK(0);
  writeK(0);
  __syncthreads();
  for (int it = 0; it < NIT; ++it) {
    const int cur = it & 1, kb = it * KSTEP;
    if (it + 1 < NIT) issueK(kb + KSTEP);
    f32x16 d = qk_tile(cur);
#pragma unroll
    for (int quad = 0; quad < 4; ++quad) {
      if (USEB) {
        const f32x4 bb = *(const f32x4*)(Br + kb + 8 * quad + 4 * h);
        rs += __expf(fmaf(d[4 * quad + 0], 0.125f, bb[0]))
            + __expf(fmaf(d[4 * quad + 1], 0.125f, bb[1]))
            + __expf(fmaf(d[4 * quad + 2], 0.125f, bb[2]))
            + __expf(fmaf(d[4 * quad + 3], 0.125f, bb[3]));
      } else {
        const int4 mm = *(const int4*)(Mr + kb + 8 * quad + 4 * h);
        rs += (mm.x ? __expf(d[4 * quad + 0] * 0.125f) : 0.f)
            + (mm.y ? __expf(d[4 * quad + 1] * 0.125f) : 0.f)
            + (mm.z ? __expf(d[4 * quad + 2] * 0.125f) : 0.f)
            + (mm.w ? __expf(d[4 * quad + 3] * 0.125f) : 0.f);
      }
    }
    if (it + 1 < NIT) writeK((it + 1) & 1);
    __syncthreads();
  }
  rs += __shfl_xor(rs, 32);
  if (lane < 32) Rs[kt][wq * 32 + q] = rs;
  issueK(0);
  issueV(0);
  __syncthreads();
  const float inv = 1.f / (Rs[0][wq * 32 + q] + Rs[1][wq * 32 + q]);
  writeK(0);
  writeV(0);
  __syncthreads();

  // ---------------- Phase 2: weights out + PV (k-half partial) ----------------
  f32x16 acc[2] = {};
  float* wrow = wts + (bq + q0 + q) * NS + kt * 32;
  for (int it = 0; it < NIT; ++it) {
    const int cur = it & 1, kb = it * KSTEP;
    if (it + 1 < NIT) { issueK(kb + KSTEP); issueV(kb + KSTEP); }

    f32x16 d = qk_tile(cur);

    u32 wpk[8];
#pragma unroll
    for (int quad = 0; quad < 4; ++quad) {
      float w0, w1, w2, w3;
      if (USEB) {
        const f32x4 bb = *(const f32x4*)(Br + kb + 8 * quad + 4 * h);
        w0 = __expf(fmaf(d[4 * quad + 0], 0.125f, bb[0])) * inv;
        w1 = __expf(fmaf(d[4 * quad + 1], 0.125f, bb[1])) * inv;
        w2 = __expf(fmaf(d[4 * quad + 2], 0.125f, bb[2])) * inv;
        w3 = __expf(fmaf(d[4 * quad + 3], 0.125f, bb[3])) * inv;
      } else {
        const int4 mm = *(const int4*)(Mr + kb + 8 * quad + 4 * h);
        w0 = mm.x ? __expf(d[4 * quad + 0] * 0.125f) * inv : 0.f;
        w1 = mm.y ? __expf(d[4 * quad + 1] * 0.125f) * inv : 0.f;
        w2 = mm.z ? __expf(d[4 * quad + 2] * 0.125f) * inv : 0.f;
        w3 = mm.w ? __expf(d[4 * quad + 3] * 0.125f) * inv : 0.f;
      }
      f32x4 wv = {w0, w1, w2, w3};
      *(f32x4*)(wrow + kb + 8 * quad + 4 * h) = wv;
      wpk[2 * quad]     = (u32)f2bs(w0) | ((u32)f2bs(w1) << 16);
      wpk[2 * quad + 1] = (u32)f2bs(w2) | ((u32)f2bs(w3) << 16);
    }

    // PV partial: A = permuted V^T tile (this k-half), B = W from registers
#pragma unroll
    for (int cc = 0; cc < 2; ++cc) {
      u32x4 wu = {wpk[4 * cc + 0], wpk[4 * cc + 1], wpk[4 * cc + 2], wpk[4 * cc + 3]};
      bf16x8 wb = __builtin_bit_cast(bf16x8, wu);
#pragma unroll
      for (int dt = 0; dt < 2; ++dt) {
        bf16x8 va = *(const bf16x8*)&Vt[cur][dt * 32 + q][16 * (2 * kt + cc) + 8 * h];
        acc[dt] = __builtin_amdgcn_mfma_f32_32x32x16_bf16(va, wb, acc[dt], 0, 0, 0);
      }
    }

    if (it + 1 < NIT) { writeK((it + 1) & 1); writeV((it + 1) & 1); }
    __syncthreads();
  }

  // ---------------- pair-combine ctx partials through LDS ----------------
  // pair p = wq uses region: pairs 0,1 in Kt, pairs 2,3 in Vt; 32x68 floats each
  float* red = ((wq < 2) ? (float*)&Kt[0][0][0] : (float*)&Vt[0][0][0]) + (wq & 1) * 2176;
  if (kt == 1) {
#pragma unroll
    for (int dt = 0; dt < 2; ++dt)
#pragma unroll
      for (int e = 0; e < 16; ++e)
        red[q * 68 + dt * 32 + (e & 3) + 8 * (e >> 2) + 4 * h] = acc[dt][e];
  }
  __syncthreads();
  if (kt == 0) {
    float* crow = ctx + (bq + q0 + q) * ND;
#pragma unroll
    for (int dt = 0; dt < 2; ++dt)
#pragma unroll
      for (int quad = 0; quad < 4; ++quad) {
        const int dbase = dt * 32 + 8 * quad + 4 * h;
        f32x4 vv;
#pragma unroll
        for (int r = 0; r < 4; ++r)
          vv[r] = acc[dt][4 * quad + r] + red[q * 68 + dbase + r];
        *(f32x4*)(crow + dbase) = vv;
      }
  }
}

extern "C" void kernel_launch(void* const* d_in, const int* in_sizes, int n_in,
                              void* d_out, int out_size, void* d_ws, size_t ws_size,
                              hipStream_t stream) {
  const float* Q = (const float*)d_in[0];
  const float* K = (const float*)d_in[1];
  const float* V = (const float*)d_in[2];
  const int*   M = (const int*)d_in[3];
  float* ctx = (float*)d_out;                         // [B,S,D]
  float* wts = (float*)d_out + (size_t)NB * NS * ND;  // [B,S,S]

  dim3 grid(NB * (NS / 128));  // 1024
  dim3 block(512);

  const size_t biasBytes = (size_t)NS * NS * sizeof(float);
  if (ws_size >= biasBytes) {
    const int n4 = NS * NS / 4;
    hipLaunchKernelGGL(mask_to_bias_kernel, dim3((n4 + 255) / 256), dim3(256), 0, stream,
                       (const int4*)M, (float4*)d_ws, n4);
    hipLaunchKernelGGL(DotProductAttention_22436909154804_kernel<true>, grid, block, 0, stream,
                       Q, K, V, M, (const float*)d_ws, ctx, wts);
  } else {
    hipLaunchKernelGGL(DotProductAttention_22436909154804_kernel<false>, grid, block, 0, stream,
                       Q, K, V, M, (const float*)nullptr, ctx, wts);
  }
}

// Round 5
// 570.451 us; speedup vs baseline: 2.7278x; 2.7278x over previous
//
#include <hip/hip_runtime.h>

#define NB 64
#define NS 2048
#define ND 64
#define KSTEP 32
#define NIT (NS / KSTEP)  // 64

typedef __bf16 bf16x8 __attribute__((ext_vector_type(8)));
typedef float f32x4 __attribute__((ext_vector_type(4)));
typedef unsigned int u32;
typedef u32 u32x2 __attribute__((ext_vector_type(2)));
typedef u32 u32x4 __attribute__((ext_vector_type(4)));

__device__ __forceinline__ unsigned short f2bs(float x) {
  __bf16 h = (__bf16)x;
  return __builtin_bit_cast(unsigned short, h);
}

__device__ __forceinline__ bf16x8 cvt8(f32x4 a, f32x4 b) {
  bf16x8 r;
  r[0] = (__bf16)a[0]; r[1] = (__bf16)a[1]; r[2] = (__bf16)a[2]; r[3] = (__bf16)a[3];
  r[4] = (__bf16)b[0]; r[5] = (__bf16)b[1]; r[6] = (__bf16)b[2]; r[7] = (__bf16)b[3];
  return r;
}

// mask (int 0/1) -> additive bias (0 / -1e9); written to d_ws once per launch
__global__ __launch_bounds__(256) void mask_to_bias_kernel(
    const int4* __restrict__ M4, float4* __restrict__ B4, int n4) {
  int i = blockIdx.x * 256 + threadIdx.x;
  if (i < n4) {
    int4 m = M4[i];
    float4 o;
    o.x = m.x ? 0.f : -1e9f;
    o.y = m.y ? 0.f : -1e9f;
    o.z = m.z ? 0.f : -1e9f;
    o.w = m.w ? 0.f : -1e9f;
    B4[i] = o;
  }
}

// mfma_f32_16x16x32_bf16 layout facts (HW-verified rounds 1-2):
//   A: lane holds A[row = l&15][k = 8*(l>>4) + s]
//   B: lane holds B[k = 8*(l>>4) + s][col = l&15]
//   D: lane holds D[m = 4*(l>>4) + reg][n = l&15]
// QK^T role-swapped (A=K, B=Q): lane owns W[q = c][k = 16j + 4g + r]
//   -> coalesced f32x4 wts stores + W feeds PV's B-operand from registers.
// PV: A = V^T staged [d][k] (cols = k directly); slot map s<4 -> k=4g+s,
//   s>=4 -> k=16+4g+(s-4) on BOTH operands (consistent bijection).
// NOTE: __launch_bounds__ 2nd arg behaves as blocks/CU for 256-thread blocks;
// round-4's (512,6) caused a 40-VGPR cap + spill catastrophe. 7 -> cap 73.
template <bool USEB>
__global__ __launch_bounds__(256, 7) void DotProductAttention_22436909154804_kernel(
    const float* __restrict__ Q, const float* __restrict__ K,
    const float* __restrict__ V, const int* __restrict__ M,
    const float* __restrict__ Bias, float* __restrict__ ctx,
    float* __restrict__ wts) {
  __shared__ __attribute__((aligned(16))) unsigned short Kt[2][32][68];  // [k][d]
  __shared__ __attribute__((aligned(16))) unsigned short Vt[2][64][36];  // [d][k]

  const int tid  = threadIdx.x;
  const int lane = tid & 63;
  const int w    = tid >> 6;   // 0..3
  const int g    = lane >> 4;  // 0..3
  const int c    = lane & 15;  // 0..15

  // XCD-bijective swizzle: 2048 blocks = 8 XCDs x 256; same-batch blocks share an XCD
  const int bid = blockIdx.x;
  const int vb  = (bid & 7) * 256 + (bid >> 3);
  const int b   = vb >> 5;
  const int qt  = vb & 31;
  const int q0w = qt * 64 + w * 16;
  const size_t bq = (size_t)b * NS;

  // Q B-frags (nt: Q rows are block-private, don't cache)
  const float* qp = Q + (bq + q0w + c) * ND + 8 * g;
  f32x4 qa = __builtin_nontemporal_load((const f32x4*)qp);
  f32x4 qb = __builtin_nontemporal_load((const f32x4*)(qp + 4));
  const bf16x8 qf0 = cvt8(qa, qb);
  qa = __builtin_nontemporal_load((const f32x4*)(qp + 32));
  qb = __builtin_nontemporal_load((const f32x4*)(qp + 36));
  const bf16x8 qf1 = cvt8(qa, qb);

  const float* Kb = K + bq * ND;
  const float* Vb = V + bq * ND;
  const int*   Mr = M + (size_t)(q0w + c) * NS;
  const float* Br = USEB ? (Bias + (size_t)(q0w + c) * NS) : nullptr;

  // staging maps (256 threads, 32x64 K tile / 32x64 V tile)
  const int skr = tid >> 3;        // K row 0..31
  const int skd = (tid & 7) * 8;   // K d-chunk
  const int svp = tid >> 4;        // V k-pair 0..15
  const int svd = (tid & 15) * 4;  // V d base

  f32x4 kst0, kst1, vst0, vst1;
  auto issueK = [&](int kb) {
    const float* p = Kb + (size_t)(kb + skr) * ND + skd;
    kst0 = *(const f32x4*)p;
    kst1 = *(const f32x4*)(p + 4);
  };
  auto writeK = [&](int buf) {
    *(bf16x8*)&Kt[buf][skr][skd] = cvt8(kst0, kst1);
  };
  auto issueV = [&](int kb) {
    const float* p = Vb + (size_t)(kb + 2 * svp) * ND + svd;
    vst0 = *(const f32x4*)p;
    vst1 = *(const f32x4*)(p + ND);
  };
  auto writeV = [&](int buf) {
#pragma unroll
    for (int j = 0; j < 4; ++j)
      *(u32*)&Vt[buf][svd + j][2 * svp] = (u32)f2bs(vst0[j]) | ((u32)f2bs(vst1[j]) << 16);
  };

  const f32x4 zz = {0.f, 0.f, 0.f, 0.f};

  // ---------------- Phase 1: row sums ----------------
  float rs = 0.f;
  issueK(0);
  writeK(0);
  __syncthreads();
  for (int it = 0; it < NIT; ++it) {
    const int cur = it & 1, kb = it * KSTEP;
    if (it + 1 < NIT) issueK(kb + KSTEP);
#pragma unroll
    for (int j = 0; j < 2; ++j) {
      bf16x8 a0 = *(const bf16x8*)&Kt[cur][16 * j + c][8 * g];
      bf16x8 a1 = *(const bf16x8*)&Kt[cur][16 * j + c][32 + 8 * g];
      f32x4 s = __builtin_amdgcn_mfma_f32_16x16x32_bf16(a0, qf0, zz, 0, 0, 0);
      s = __builtin_amdgcn_mfma_f32_16x16x32_bf16(a1, qf1, s, 0, 0, 0);
      if (USEB) {
        const f32x4 bb = *(const f32x4*)(Br + kb + 16 * j + 4 * g);
        rs += __expf(fmaf(s[0], 0.125f, bb[0])) + __expf(fmaf(s[1], 0.125f, bb[1]))
            + __expf(fmaf(s[2], 0.125f, bb[2])) + __expf(fmaf(s[3], 0.125f, bb[3]));
      } else {
        const int4 mm = *(const int4*)(Mr + kb + 16 * j + 4 * g);
        rs += (mm.x ? __expf(s[0] * 0.125f) : 0.f)
            + (mm.y ? __expf(s[1] * 0.125f) : 0.f)
            + (mm.z ? __expf(s[2] * 0.125f) : 0.f)
            + (mm.w ? __expf(s[3] * 0.125f) : 0.f);
      }
    }
    if (it + 1 < NIT) writeK((it + 1) & 1);
    __syncthreads();
  }
  rs += __shfl_xor(rs, 16);
  rs += __shfl_xor(rs, 32);
  const float inv = 1.f / rs;

  // ---------------- Phase 2: weights out + PV ----------------
  f32x4 acc[4] = {zz, zz, zz, zz};
  issueK(0); issueV(0);
  writeK(0); writeV(0);
  __syncthreads();
  float* wrow = wts + (bq + q0w + c) * NS;
  for (int it = 0; it < NIT; ++it) {
    const int cur = it & 1, kb = it * KSTEP;
    if (it + 1 < NIT) { issueK(kb + KSTEP); issueV(kb + KSTEP); }

    u32 wpk[4];
#pragma unroll
    for (int j = 0; j < 2; ++j) {
      bf16x8 a0 = *(const bf16x8*)&Kt[cur][16 * j + c][8 * g];
      bf16x8 a1 = *(const bf16x8*)&Kt[cur][16 * j + c][32 + 8 * g];
      f32x4 s = __builtin_amdgcn_mfma_f32_16x16x32_bf16(a0, qf0, zz, 0, 0, 0);
      s = __builtin_amdgcn_mfma_f32_16x16x32_bf16(a1, qf1, s, 0, 0, 0);
      float w0, w1, w2, w3;
      if (USEB) {
        const f32x4 bb = *(const f32x4*)(Br + kb + 16 * j + 4 * g);
        w0 = __expf(fmaf(s[0], 0.125f, bb[0])) * inv;
        w1 = __expf(fmaf(s[1], 0.125f, bb[1])) * inv;
        w2 = __expf(fmaf(s[2], 0.125f, bb[2])) * inv;
        w3 = __expf(fmaf(s[3], 0.125f, bb[3])) * inv;
      } else {
        const int4 mm = *(const int4*)(Mr + kb + 16 * j + 4 * g);
        w0 = mm.x ? __expf(s[0] * 0.125f) * inv : 0.f;
        w1 = mm.y ? __expf(s[1] * 0.125f) * inv : 0.f;
        w2 = mm.z ? __expf(s[2] * 0.125f) * inv : 0.f;
        w3 = mm.w ? __expf(s[3] * 0.125f) * inv : 0.f;
      }
      f32x4 wv = {w0, w1, w2, w3};
      __builtin_nontemporal_store(wv, (f32x4*)(wrow + kb + 16 * j + 4 * g));
      wpk[2 * j]     = (u32)f2bs(w0) | ((u32)f2bs(w1) << 16);
      wpk[2 * j + 1] = (u32)f2bs(w2) | ((u32)f2bs(w3) << 16);
    }

    // PV: one MFMA per d-tile covers all 32 k; B = W from registers
    u32x4 wu = {wpk[0], wpk[1], wpk[2], wpk[3]};
    bf16x8 wb = __builtin_bit_cast(bf16x8, wu);
#pragma unroll
    for (int dt = 0; dt < 4; ++dt) {
      u32x2 vlo = *(const u32x2*)&Vt[cur][dt * 16 + c][4 * g];
      u32x2 vhi = *(const u32x2*)&Vt[cur][dt * 16 + c][16 + 4 * g];
      u32x4 vau = {vlo.x, vlo.y, vhi.x, vhi.y};
      acc[dt] = __builtin_amdgcn_mfma_f32_16x16x32_bf16(
          __builtin_bit_cast(bf16x8, vau), wb, acc[dt], 0, 0, 0);
    }

    if (it + 1 < NIT) { writeK((it + 1) & 1); writeV((it + 1) & 1); }
    __syncthreads();
  }

  // ctx store: lane holds ctx[q0w+c][dt*16 + 4g + r]
  float* crow = ctx + (bq + q0w + c) * ND;
#pragma unroll
  for (int dt = 0; dt < 4; ++dt)
    __builtin_nontemporal_store(acc[dt], (f32x4*)(crow + dt * 16 + 4 * g));
}

extern "C" void kernel_launch(void* const* d_in, const int* in_sizes, int n_in,
                              void* d_out, int out_size, void* d_ws, size_t ws_size,
                              hipStream_t stream) {
  const float* Q = (const float*)d_in[0];
  const float* K = (const float*)d_in[1];
  const float* V = (const float*)d_in[2];
  const int*   M = (const int*)d_in[3];
  float* ctx = (float*)d_out;                         // [B,S,D]
  float* wts = (float*)d_out + (size_t)NB * NS * ND;  // [B,S,S]

  dim3 grid(NB * (NS / 64));  // 2048
  dim3 block(256);

  const size_t biasBytes = (size_t)NS * NS * sizeof(float);
  if (ws_size >= biasBytes) {
    const int n4 = NS * NS / 4;
    hipLaunchKernelGGL(mask_to_bias_kernel, dim3((n4 + 255) / 256), dim3(256), 0, stream,
                       (const int4*)M, (float4*)d_ws, n4);
    hipLaunchKernelGGL(DotProductAttention_22436909154804_kernel<true>, grid, block, 0, stream,
                       Q, K, V, M, (const float*)d_ws, ctx, wts);
  } else {
    hipLaunchKernelGGL(DotProductAttention_22436909154804_kernel<false>, grid, block, 0, stream,
                       Q, K, V, M, (const float*)nullptr, ctx, wts);
  }
}

// Round 6
// 427.072 us; speedup vs baseline: 3.6436x; 1.3357x over previous
//
#include <hip/hip_runtime.h>

#define NB 64
#define NS 2048
#define ND 64
#define KSTEP 32
#define NIT (NS / KSTEP)  // 64

typedef __bf16 bf16x8 __attribute__((ext_vector_type(8)));
typedef float f32x4 __attribute__((ext_vector_type(4)));
typedef unsigned int u32;
typedef u32 u32x2 __attribute__((ext_vector_type(2)));
typedef u32 u32x4 __attribute__((ext_vector_type(4)));

__device__ __forceinline__ unsigned short f2bs(float x) {
  __bf16 h = (__bf16)x;
  return __builtin_bit_cast(unsigned short, h);
}

__device__ __forceinline__ bf16x8 cvt8(f32x4 a, f32x4 b) {
  bf16x8 r;
  r[0] = (__bf16)a[0]; r[1] = (__bf16)a[1]; r[2] = (__bf16)a[2]; r[3] = (__bf16)a[3];
  r[4] = (__bf16)b[0]; r[5] = (__bf16)b[1]; r[6] = (__bf16)b[2]; r[7] = (__bf16)b[3];
  return r;
}

// mask (int 0/1) -> additive bias (0 / -1e9); written to d_ws once per launch
__global__ __launch_bounds__(256) void mask_to_bias_kernel(
    const int4* __restrict__ M4, float4* __restrict__ B4, int n4) {
  int i = blockIdx.x * 256 + threadIdx.x;
  if (i < n4) {
    int4 m = M4[i];
    float4 o;
    o.x = m.x ? 0.f : -1e9f;
    o.y = m.y ? 0.f : -1e9f;
    o.z = m.z ? 0.f : -1e9f;
    o.w = m.w ? 0.f : -1e9f;
    B4[i] = o;
  }
}

// mfma_f32_16x16x32_bf16 layout facts (HW-verified rounds 1-2):
//   A: lane holds A[row = l&15][k = 8*(l>>4) + s]
//   B: lane holds B[k = 8*(l>>4) + s][col = l&15]
//   D: lane holds D[m = 4*(l>>4) + reg][n = l&15]
// QK^T role-swapped (A=K, B=Q): lane owns W[q = c][k = 16j + 4g + r]
//   -> coalesced f32x4 wts stores + W feeds PV's B-operand from registers.
// 8 waves x 16 q-rows = 128 q-rows/block (1024 blocks): halves logical K/V
// re-reads vs 64-row blocks. Phase-2 staging split by wave role: waves 0-3
// stage K, waves 4-7 stage V (wave-uniform).
// NOTE: __launch_bounds__ second arg is POISON for 512-thread blocks
// (round 4: (512,6) -> 40-VGPR cap -> scratch spill catastrophe). None here.
template <bool USEB>
__global__ __launch_bounds__(512) void DotProductAttention_22436909154804_kernel(
    const float* __restrict__ Q, const float* __restrict__ K,
    const float* __restrict__ V, const int* __restrict__ M,
    const float* __restrict__ Bias, float* __restrict__ ctx,
    float* __restrict__ wts) {
  __shared__ __attribute__((aligned(16))) unsigned short Kt[2][32][68];  // [k][d]
  __shared__ __attribute__((aligned(16))) unsigned short Vt[2][64][36];  // [d][k]

  const int tid  = threadIdx.x;
  const int lane = tid & 63;
  const int w    = tid >> 6;   // 0..7
  const int g    = lane >> 4;  // 0..3
  const int c    = lane & 15;  // 0..15

  // XCD-bijective swizzle: 1024 blocks = 8 XCDs x 128; same-batch blocks share an XCD
  const int bid = blockIdx.x;
  const int vb  = (bid & 7) * 128 + (bid >> 3);
  const int b   = vb >> 4;
  const int qt  = vb & 15;
  const int q0w = qt * 128 + w * 16;
  const size_t bq = (size_t)b * NS;

  // Q B-frags (nt: block-private rows)
  const float* qp = Q + (bq + q0w + c) * ND + 8 * g;
  f32x4 qa = __builtin_nontemporal_load((const f32x4*)qp);
  f32x4 qb = __builtin_nontemporal_load((const f32x4*)(qp + 4));
  const bf16x8 qf0 = cvt8(qa, qb);
  qa = __builtin_nontemporal_load((const f32x4*)(qp + 32));
  qb = __builtin_nontemporal_load((const f32x4*)(qp + 36));
  const bf16x8 qf1 = cvt8(qa, qb);

  const float* Kb = K + bq * ND;
  const float* Vb = V + bq * ND;
  const int*   Mr = M + (size_t)(q0w + c) * NS;
  const float* Br = USEB ? (Bias + (size_t)(q0w + c) * NS) : nullptr;

  // staging role split: threads 0-255 (waves 0-3) stage K; 256-511 stage V
  const bool isK = (tid < 256);
  const int st   = tid & 255;
  const int skr = st >> 3;         // K row 0..31
  const int skd = (st & 7) * 8;    // K d-chunk
  const int svp = st >> 4;         // V k-pair 0..15
  const int svd = (st & 15) * 4;   // V d base

  f32x4 st0, st1;
  auto issueK1 = [&](int kb) {  // phase 1: K only, by K-threads
    if (isK) {
      const float* p = Kb + (size_t)(kb + skr) * ND + skd;
      st0 = *(const f32x4*)p;
      st1 = *(const f32x4*)(p + 4);
    }
  };
  auto writeK1 = [&](int buf) {
    if (isK) *(bf16x8*)&Kt[buf][skr][skd] = cvt8(st0, st1);
  };
  auto issueKV = [&](int kb) {  // phase 2: role-split K/V staging
    if (isK) {
      const float* p = Kb + (size_t)(kb + skr) * ND + skd;
      st0 = *(const f32x4*)p;
      st1 = *(const f32x4*)(p + 4);
    } else {
      const float* p = Vb + (size_t)(kb + 2 * svp) * ND + svd;
      st0 = *(const f32x4*)p;
      st1 = *(const f32x4*)(p + ND);
    }
  };
  auto writeKV = [&](int buf) {
    if (isK) {
      *(bf16x8*)&Kt[buf][skr][skd] = cvt8(st0, st1);
    } else {
#pragma unroll
      for (int j = 0; j < 4; ++j)
        *(u32*)&Vt[buf][svd + j][2 * svp] = (u32)f2bs(st0[j]) | ((u32)f2bs(st1[j]) << 16);
    }
  };

  const f32x4 zz = {0.f, 0.f, 0.f, 0.f};

  // ---------------- Phase 1: row sums ----------------
  float rs = 0.f;
  issueK1(0);
  writeK1(0);
  __syncthreads();
  for (int it = 0; it < NIT; ++it) {
    const int cur = it & 1, kb = it * KSTEP;
    if (it + 1 < NIT) issueK1(kb + KSTEP);
#pragma unroll
    for (int j = 0; j < 2; ++j) {
      bf16x8 a0 = *(const bf16x8*)&Kt[cur][16 * j + c][8 * g];
      bf16x8 a1 = *(const bf16x8*)&Kt[cur][16 * j + c][32 + 8 * g];
      f32x4 s = __builtin_amdgcn_mfma_f32_16x16x32_bf16(a0, qf0, zz, 0, 0, 0);
      s = __builtin_amdgcn_mfma_f32_16x16x32_bf16(a1, qf1, s, 0, 0, 0);
      if (USEB) {
        const f32x4 bb = *(const f32x4*)(Br + kb + 16 * j + 4 * g);
        rs += __expf(fmaf(s[0], 0.125f, bb[0])) + __expf(fmaf(s[1], 0.125f, bb[1]))
            + __expf(fmaf(s[2], 0.125f, bb[2])) + __expf(fmaf(s[3], 0.125f, bb[3]));
      } else {
        const int4 mm = *(const int4*)(Mr + kb + 16 * j + 4 * g);
        rs += (mm.x ? __expf(s[0] * 0.125f) : 0.f)
            + (mm.y ? __expf(s[1] * 0.125f) : 0.f)
            + (mm.z ? __expf(s[2] * 0.125f) : 0.f)
            + (mm.w ? __expf(s[3] * 0.125f) : 0.f);
      }
    }
    if (it + 1 < NIT) writeK1((it + 1) & 1);
    __syncthreads();
  }
  rs += __shfl_xor(rs, 16);
  rs += __shfl_xor(rs, 32);
  const float inv = 1.f / rs;

  // ---------------- Phase 2: weights out + PV ----------------
  f32x4 acc[4] = {zz, zz, zz, zz};
  issueKV(0);
  writeKV(0);
  __syncthreads();
  float* wrow = wts + (bq + q0w + c) * NS;
  for (int it = 0; it < NIT; ++it) {
    const int cur = it & 1, kb = it * KSTEP;
    if (it + 1 < NIT) issueKV(kb + KSTEP);

    u32 wpk[4];
#pragma unroll
    for (int j = 0; j < 2; ++j) {
      bf16x8 a0 = *(const bf16x8*)&Kt[cur][16 * j + c][8 * g];
      bf16x8 a1 = *(const bf16x8*)&Kt[cur][16 * j + c][32 + 8 * g];
      f32x4 s = __builtin_amdgcn_mfma_f32_16x16x32_bf16(a0, qf0, zz, 0, 0, 0);
      s = __builtin_amdgcn_mfma_f32_16x16x32_bf16(a1, qf1, s, 0, 0, 0);
      float w0, w1, w2, w3;
      if (USEB) {
        const f32x4 bb = *(const f32x4*)(Br + kb + 16 * j + 4 * g);
        w0 = __expf(fmaf(s[0], 0.125f, bb[0])) * inv;
        w1 = __expf(fmaf(s[1], 0.125f, bb[1])) * inv;
        w2 = __expf(fmaf(s[2], 0.125f, bb[2])) * inv;
        w3 = __expf(fmaf(s[3], 0.125f, bb[3])) * inv;
      } else {
        const int4 mm = *(const int4*)(Mr + kb + 16 * j + 4 * g);
        w0 = mm.x ? __expf(s[0] * 0.125f) * inv : 0.f;
        w1 = mm.y ? __expf(s[1] * 0.125f) * inv : 0.f;
        w2 = mm.z ? __expf(s[2] * 0.125f) * inv : 0.f;
        w3 = mm.w ? __expf(s[3] * 0.125f) * inv : 0.f;
      }
      f32x4 wv = {w0, w1, w2, w3};
      __builtin_nontemporal_store(wv, (f32x4*)(wrow + kb + 16 * j + 4 * g));
      wpk[2 * j]     = (u32)f2bs(w0) | ((u32)f2bs(w1) << 16);
      wpk[2 * j + 1] = (u32)f2bs(w2) | ((u32)f2bs(w3) << 16);
    }

    // PV: one MFMA per d-tile covers all 32 k; B = W from registers
    u32x4 wu = {wpk[0], wpk[1], wpk[2], wpk[3]};
    bf16x8 wb = __builtin_bit_cast(bf16x8, wu);
#pragma unroll
    for (int dt = 0; dt < 4; ++dt) {
      u32x2 vlo = *(const u32x2*)&Vt[cur][dt * 16 + c][4 * g];
      u32x2 vhi = *(const u32x2*)&Vt[cur][dt * 16 + c][16 + 4 * g];
      u32x4 vau = {vlo.x, vlo.y, vhi.x, vhi.y};
      acc[dt] = __builtin_amdgcn_mfma_f32_16x16x32_bf16(
          __builtin_bit_cast(bf16x8, vau), wb, acc[dt], 0, 0, 0);
    }

    if (it + 1 < NIT) writeKV((it + 1) & 1);
    __syncthreads();
  }

  // ctx store: lane holds ctx[q0w+c][dt*16 + 4g + r]
  float* crow = ctx + (bq + q0w + c) * ND;
#pragma unroll
  for (int dt = 0; dt < 4; ++dt)
    __builtin_nontemporal_store(acc[dt], (f32x4*)(crow + dt * 16 + 4 * g));
}

extern "C" void kernel_launch(void* const* d_in, const int* in_sizes, int n_in,
                              void* d_out, int out_size, void* d_ws, size_t ws_size,
                              hipStream_t stream) {
  const float* Q = (const float*)d_in[0];
  const float* K = (const float*)d_in[1];
  const float* V = (const float*)d_in[2];
  const int*   M = (const int*)d_in[3];
  float* ctx = (float*)d_out;                         // [B,S,D]
  float* wts = (float*)d_out + (size_t)NB * NS * ND;  // [B,S,S]

  dim3 grid(NB * (NS / 128));  // 1024
  dim3 block(512);

  const size_t biasBytes = (size_t)NS * NS * sizeof(float);
  if (ws_size >= biasBytes) {
    const int n4 = NS * NS / 4;
    hipLaunchKernelGGL(mask_to_bias_kernel, dim3((n4 + 255) / 256), dim3(256), 0, stream,
                       (const int4*)M, (float4*)d_ws, n4);
    hipLaunchKernelGGL(DotProductAttention_22436909154804_kernel<true>, grid, block, 0, stream,
                       Q, K, V, M, (const float*)d_ws, ctx, wts);
  } else {
    hipLaunchKernelGGL(DotProductAttention_22436909154804_kernel<false>, grid, block, 0, stream,
                       Q, K, V, M, (const float*)nullptr, ctx, wts);
  }
}